// Round 4
// baseline (560.682 us; speedup 1.0000x reference)
//
#include <hip/hip_runtime.h>
#include <math.h>

#define Bb 32
#define Pp 1024
#define Nn 1024

typedef unsigned short u16;
typedef __bf16 bf16x8 __attribute__((ext_vector_type(8)));
typedef float f32x4 __attribute__((ext_vector_type(4)));
typedef u16 us8 __attribute__((ext_vector_type(8)));
typedef u16 us4 __attribute__((ext_vector_type(4)));

#define MFMA __builtin_amdgcn_mfma_f32_16x16x32_bf16

static constexpr float INV_SQRT_E = 0.08838834764831845f;  // 1/sqrt(128)

__device__ __forceinline__ bf16x8 asbf(us8 v) { return __builtin_bit_cast(bf16x8, v); }

// split x into bf16 hi + bf16 lo (RTN), x ~= hi + lo to ~2^-17 rel
__device__ __forceinline__ void bsplit(float x, u16& h, u16& l) {
  unsigned u = __float_as_uint(x);
  unsigned r = u + 0x7FFF + ((u >> 16) & 1);
  h = (u16)(r >> 16);
  float hf = __uint_as_float((unsigned)h << 16);
  float lof = x - hf;
  unsigned u2 = __float_as_uint(lof);
  unsigned r2 = u2 + 0x7FFF + ((u2 >> 16) & 1);
  l = (u16)(r2 >> 16);
}

__device__ __forceinline__ void bsplit4(float a, float bq, float c, float d,
                                        us4& h4, us4& l4) {
  u16 h, l;
  bsplit(a, h, l); h4[0] = h; l4[0] = l;
  bsplit(bq, h, l); h4[1] = h; l4[1] = l;
  bsplit(c, h, l); h4[2] = h; l4[2] = l;
  bsplit(d, h, l); h4[3] = h; l4[3] = l;
}

__device__ __forceinline__ float fast_tanh(float x) {
  float ax = fabsf(x);
  float t = __expf(-2.0f * ax);
  float r = (1.0f - t) / (1.0f + t);
  return copysignf(r, x);
}

// ---------------- K0: transposed split weight planes ----------------
__global__ __launch_bounds__(256) void prep_weights(
    const float* __restrict__ Wq1, const float* __restrict__ Wq2,
    const float* __restrict__ Wql, const float* __restrict__ Wk,
    const float* __restrict__ Wv, u16* __restrict__ wcat_hi, u16* __restrict__ wcat_lo,
    u16* __restrict__ wkv_hi, u16* __restrict__ wkv_lo) {
  int t = threadIdx.x;
  if (blockIdx.x == 0) {
    for (int i = t; i < 128 * 384; i += 256) {
      int c = i / 384, k = i % 384;
      float v = (k < 128) ? Wq1[k * 128 + c]
                          : (k < 256) ? Wq2[(k - 128) * 128 + c] : Wql[(k - 256) * 128 + c];
      u16 h, l;
      bsplit(v, h, l);
      wcat_hi[i] = h;
      wcat_lo[i] = l;
    }
  } else {
    for (int i = t; i < 256 * 128; i += 256) {
      int c = i >> 7, k = i & 127;
      float v = (c < 128) ? Wk[k * 128 + c] : Wv[k * 128 + (c - 128)];
      u16 h, l;
      bsplit(v, h, l);
      wkv_hi[i] = h;
      wkv_lo[i] = l;
    }
  }
}

// ---------------- K1: k/v GEMM (split MFMA) -> ekkT planes + nodesP planes ----------------
__global__ __launch_bounds__(256, 1) void kv_prep(
    const float* __restrict__ nodes, const u16* __restrict__ wkv_hi,
    const u16* __restrict__ wkv_lo, u16* __restrict__ ekkT_hi, u16* __restrict__ ekkT_lo,
    u16* __restrict__ nodesP_hi, u16* __restrict__ nodesP_lo) {
  __shared__ u16 a_hi[32 * 136], a_lo[32 * 136];
  __shared__ float kvbuf[32 * 264];
  const int t = threadIdx.x;
  const int b = blockIdx.x >> 5;
  const int n0 = (blockIdx.x & 31) * 32;
  for (int i = t; i < 4096; i += 256) {
    int n = i >> 7, d = i & 127;
    float v = nodes[((long)(b * 1024 + n0 + n)) * 128 + d];
    u16 h, l;
    bsplit(v, h, l);
    a_hi[n * 136 + d] = h;
    a_lo[n * 136 + d] = l;
  }
  __syncthreads();
  const int lane = t & 63, w = t >> 6;
  const int lr = lane & 15, lg = lane >> 4;
  f32x4 acc0[2][4] = {}, acc1[2][4] = {};
#pragma unroll
  for (int ks = 0; ks < 4; ++ks) {
    us8 ah[2], al[2];
#pragma unroll
    for (int mt = 0; mt < 2; ++mt) {
      int ro = (lr + 16 * mt) * 136 + ks * 32 + lg * 8;
      ah[mt] = *(const us8*)&a_hi[ro];
      al[mt] = *(const us8*)&a_lo[ro];
    }
    us8 bh[4], bl[4];
#pragma unroll
    for (int cc = 0; cc < 4; ++cc) {
      long off = (long)((w * 4 + cc) * 16 + lr) * 128 + ks * 32 + lg * 8;
      bh[cc] = *(const us8*)&wkv_hi[off];
      bl[cc] = *(const us8*)&wkv_lo[off];
    }
#pragma unroll
    for (int mt = 0; mt < 2; ++mt)
#pragma unroll
      for (int cc = 0; cc < 4; ++cc) {
        acc0[mt][cc] = MFMA(asbf(ah[mt]), asbf(bh[cc]), acc0[mt][cc], 0, 0, 0);
        acc1[mt][cc] = MFMA(asbf(al[mt]), asbf(bh[cc]), acc1[mt][cc], 0, 0, 0);
        acc1[mt][cc] = MFMA(asbf(ah[mt]), asbf(bl[cc]), acc1[mt][cc], 0, 0, 0);
      }
  }
#pragma unroll
  for (int mt = 0; mt < 2; ++mt)
#pragma unroll
    for (int cc = 0; cc < 4; ++cc) {
      int c = (w * 4 + cc) * 16 + lr;
#pragma unroll
      for (int r = 0; r < 4; ++r)
        kvbuf[(lg * 4 + r + 16 * mt) * 264 + c] = acc0[mt][cc][r] + acc1[mt][cc][r];
    }
  __syncthreads();
#pragma unroll
  for (int jo = 0; jo < 4; ++jo) {
    int j = jo * 64 + (t >> 2);
    int i4 = t & 3;
    int kcol = (j < 128) ? j : (j - 128);
    us8 h8, l8;
#pragma unroll
    for (int jj = 0; jj < 8; ++jj) {
      int n = i4 * 8 + jj;
      float kv = kvbuf[n * 264 + kcol];
      float ek = __expf(kv);
      float val = (j < 128) ? ek * kvbuf[n * 264 + j + 128] : ek;
      u16 h, l;
      bsplit(val, h, l);
      h8[jj] = h;
      l8[jj] = l;
    }
    long o = ((long)(b * 256 + j)) * 1024 + n0 + i4 * 8;
    *(us8*)&ekkT_hi[o] = h8;
    *(us8*)&ekkT_lo[o] = l8;
  }
  {
    int pl = t >> 7, r = t & 127;
    int dgrp = r >> 3, nb = r & 7;
    const u16* src = pl ? a_lo : a_hi;
    u16* dst = pl ? nodesP_lo : nodesP_hi;
#pragma unroll
    for (int i = 0; i < 4; ++i) {
      int n = nb + 8 * i;
      us8 v = *(const us8*)&src[n * 136 + dgrp * 8];
      *(us8*)&dst[(((long)(b * 16 + dgrp)) * 1024 + n0 + n) * 8] = v;
    }
  }
}

// ---------------- main fused kernel: 64 p-rows per block, 512 threads ----------------
// LDS 69376 B -> 2 blocks/CU; target VGPR<=128 (launch_bounds 512,4).
__global__ __launch_bounds__(512, 4) void main_kernel(
    const float* __restrict__ q1m, const float* __restrict__ q2m,
    const float* __restrict__ lnm, const float* __restrict__ loadv,
    const float* __restrict__ leftv, const float* __restrict__ cdist,
    const float* __restrict__ ninf, const float* __restrict__ Wql,
    const u16* __restrict__ wcat_hi, const u16* __restrict__ wcat_lo,
    const u16* __restrict__ ekkT_hi, const u16* __restrict__ ekkT_lo,
    const u16* __restrict__ nodesP_hi, const u16* __restrict__ nodesP_lo,
    float* __restrict__ out, const float* __restrict__ logs,
    const float* __restrict__ aal, const float* __restrict__ pal) {
  __shared__ __align__(16) char smem_raw[69376];
  u16* fr_base = (u16*)smem_raw;                  // frag dbuf: hi at buf*4096, lo +2048 (u16 idx)
  _Float16* denb = (_Float16*)smem_raw;           // [64][128] alias of frag region (post-P2)
  _Float16* qbuf = (_Float16*)(smem_raw + 16384); // [64][132] sigmoid(q)
  u16* aft_hi = (u16*)(smem_raw + 33280);         // [64][132]
  u16* aft_lo = (u16*)(smem_raw + 50176);         // [64][132]
  float* psum = (float*)(smem_raw + 67072);       // [64][8]
  float* invb = (float*)(smem_raw + 69120);       // [64]

  const int t = threadIdx.x;
  const int lane = t & 63, w = t >> 6;
  const int lr = lane & 15, lg = lane >> 4;
  const int xcd = blockIdx.x & 7, j = blockIdx.x >> 3;
  const int b = xcd * 4 + (j >> 4);        // 4 batches per XCD -> ekkT/nodesP L2 locality
  const int p0 = (j & 15) * 64;
  const long bp = (long)b * Pp + p0;
  const float ls = logs[0];
  const float c1 = ls * aal[0], c2 = ls * pal[0];

  // staging mapping: row sp = t>>3, quad nq = t&7 covers 4 contiguous k/n elems
  const int sp = t >> 3, nq = t & 7;
  const int fw_base = ((sp >> 4) * 64 + (nq >> 1) * 16 + (sp & 15)) * 8 + (nq & 1) * 4;

  // ================= P1: q = [q1|q2|last]@Wcat, + rank-2, sigmoid -> qbuf =================
  {
    f32x4 qacc[4] = {};
    {  // prologue: stage 0 from q1m
      const float4 v = *(const float4*)&q1m[(bp + sp) * 128 + nq * 4];
      us4 h4, l4;
      bsplit4(v.x, v.y, v.z, v.w, h4, l4);
      *(us4*)&fr_base[fw_base] = h4;
      *(us4*)&fr_base[2048 + fw_base] = l4;
    }
    __syncthreads();
#pragma unroll 2
    for (int s = 0; s < 12; ++s) {
      if (s < 11) {
        int s1 = s + 1;
        const float* src = (s1 < 4) ? q1m : (s1 < 8) ? q2m : lnm;
        const float4 v = *(const float4*)&src[(bp + sp) * 128 + (s1 & 3) * 32 + nq * 4];
        us4 h4, l4;
        bsplit4(v.x, v.y, v.z, v.w, h4, l4);
        u16* fb = fr_base + ((s1 & 1) ? 4096 : 0);
        *(us4*)&fb[fw_base] = h4;
        *(us4*)&fb[2048 + fw_base] = l4;
      }
      long bo = (long)(w * 16 + lr) * 384 + s * 32 + lg * 8;
      us8 bh = *(const us8*)&wcat_hi[bo];
      us8 bl = *(const us8*)&wcat_lo[bo];
      const u16* fh = fr_base + ((s & 1) ? 4096 : 0);
      const u16* fl = fh + 2048;
#pragma unroll
      for (int mt = 0; mt < 4; ++mt) {
        us8 ah = *(const us8*)&fh[(mt * 64 + lane) * 8];
        us8 al = *(const us8*)&fl[(mt * 64 + lane) * 8];
        qacc[mt] = MFMA(asbf(ah), asbf(bh), qacc[mt], 0, 0, 0);
        qacc[mt] = MFMA(asbf(al), asbf(bh), qacc[mt], 0, 0, 0);
        qacc[mt] = MFMA(asbf(ah), asbf(bl), qacc[mt], 0, 0, 0);
      }
      __syncthreads();
    }
    int c = w * 16 + lr;
    float wl1 = Wql[128 * 128 + c], wl2 = Wql[129 * 128 + c];
#pragma unroll
    for (int mt = 0; mt < 4; ++mt)
#pragma unroll
      for (int r = 0; r < 4; ++r) {
        int row = mt * 16 + lg * 4 + r;
        float qv = qacc[mt][r] + loadv[bp + row] * wl1 + leftv[bp + row] * wl2;
        qbuf[row * 132 + c] = (_Float16)(1.0f / (1.0f + __expf(-qv)));
      }
  }

  // ================= P2: [num|den] = e_bias @ ekkT^T, K=1024 in 32 stages =================
  f32x4 acc[4][2] = {};
  {
    const long rowo = (bp + sp) * (long)Nn;
    float4 dd = *(const float4*)&cdist[rowo + nq * 4];
    float4 nn2 = *(const float4*)&ninf[rowo + nq * 4];
    {  // prologue: eb(0) -> buf0
      us4 h4, l4;
      bsplit4(__expf(fmaf(-c1, dd.x, nn2.x)), __expf(fmaf(-c1, dd.y, nn2.y)),
              __expf(fmaf(-c1, dd.z, nn2.z)), __expf(fmaf(-c1, dd.w, nn2.w)), h4, l4);
      *(us4*)&fr_base[fw_base] = h4;
      *(us4*)&fr_base[2048 + fw_base] = l4;
    }
    dd = *(const float4*)&cdist[rowo + 32 + nq * 4];
    nn2 = *(const float4*)&ninf[rowo + 32 + nq * 4];
    __syncthreads();
#pragma unroll 2
    for (int s = 0; s < 32; ++s) {
      us8 Bh[2], Bl[2];
#pragma unroll
      for (int ct = 0; ct < 2; ++ct) {
        long ro = ((long)(b * 256 + (w * 2 + ct) * 16 + lr)) * 1024 + s * 32 + lg * 8;
        Bh[ct] = *(const us8*)&ekkT_hi[ro];
        Bl[ct] = *(const us8*)&ekkT_lo[ro];
      }
      if (s < 31) {
        float4 d = dd, n = nn2;
        if (s < 30) {
          dd = *(const float4*)&cdist[rowo + (s + 2) * 32 + nq * 4];
          nn2 = *(const float4*)&ninf[rowo + (s + 2) * 32 + nq * 4];
        }
        us4 h4, l4;
        bsplit4(__expf(fmaf(-c1, d.x, n.x)), __expf(fmaf(-c1, d.y, n.y)),
                __expf(fmaf(-c1, d.z, n.z)), __expf(fmaf(-c1, d.w, n.w)), h4, l4);
        u16* fb = fr_base + (((s + 1) & 1) ? 4096 : 0);
        *(us4*)&fb[fw_base] = h4;
        *(us4*)&fb[2048 + fw_base] = l4;
      }
      const u16* fh = fr_base + ((s & 1) ? 4096 : 0);
      const u16* fl = fh + 2048;
#pragma unroll
      for (int mt = 0; mt < 4; ++mt) {
        us8 ah = *(const us8*)&fh[(mt * 64 + lane) * 8];
        us8 al = *(const us8*)&fl[(mt * 64 + lane) * 8];
#pragma unroll
        for (int ct = 0; ct < 2; ++ct) {
          acc[mt][ct] = MFMA(asbf(ah), asbf(Bh[ct]), acc[mt][ct], 0, 0, 0);
          acc[mt][ct] = MFMA(asbf(al), asbf(Bh[ct]), acc[mt][ct], 0, 0, 0);
          acc[mt][ct] = MFMA(asbf(ah), asbf(Bl[ct]), acc[mt][ct], 0, 0, 0);
        }
      }
      __syncthreads();
    }
  }

  // ================= P3: den -> LDS f16 (x2^-6); AFT = sig*num/den -> split bf16 =========
  if (w >= 4) {
#pragma unroll
    for (int mt = 0; mt < 4; ++mt)
#pragma unroll
      for (int ct = 0; ct < 2; ++ct) {
        int dcol = (w * 2 + ct) * 16 + lr - 128;
#pragma unroll
        for (int r = 0; r < 4; ++r) {
          int row = mt * 16 + lg * 4 + r;
          denb[row * 128 + dcol] = (_Float16)(acc[mt][ct][r] * 0.015625f);
        }
      }
  }
  __syncthreads();
  if (w < 4) {
#pragma unroll
    for (int mt = 0; mt < 4; ++mt)
#pragma unroll
      for (int ct = 0; ct < 2; ++ct) {
        int col = (w * 2 + ct) * 16 + lr;
#pragma unroll
        for (int r = 0; r < 4; ++r) {
          int row = mt * 16 + lg * 4 + r;
          float den = (float)denb[row * 128 + col];
          float sig = (float)qbuf[row * 132 + col];
          float aftv = sig * (acc[mt][ct][r] * 0.015625f) / (den + 1.5625e-22f);
          u16 h, l;
          bsplit(aftv, h, l);
          aft_hi[row * 132 + col] = h;
          aft_lo[row * 132 + col] = l;
        }
      }
  }
  __syncthreads();

  // ================= P4+P5: score GEMM + softmax, two 32-row passes =================
#pragma unroll 1
  for (int pass = 0; pass < 2; ++pass) {
    f32x4 sacc[2][8] = {};
#pragma unroll
    for (int ks = 0; ks < 4; ++ks) {
      us8 ah[2], al[2];
#pragma unroll
      for (int mt = 0; mt < 2; ++mt) {
        int row = pass * 32 + mt * 16 + lr;
        ah[mt] = *(const us8*)&aft_hi[row * 132 + ks * 32 + lg * 8];
        al[mt] = *(const us8*)&aft_lo[row * 132 + ks * 32 + lg * 8];
      }
#pragma unroll
      for (int jn = 0; jn < 8; ++jn) {
        long o = (((long)(b * 16 + ks * 4 + lg)) * 1024 + w * 128 + jn * 16 + lr) * 8;
        us8 bh = *(const us8*)&nodesP_hi[o];
        us8 bl = *(const us8*)&nodesP_lo[o];
#pragma unroll
        for (int mt = 0; mt < 2; ++mt) {
          sacc[mt][jn] = MFMA(asbf(ah[mt]), asbf(bh), sacc[mt][jn], 0, 0, 0);
          sacc[mt][jn] = MFMA(asbf(al[mt]), asbf(bh), sacc[mt][jn], 0, 0, 0);
          sacc[mt][jn] = MFMA(asbf(ah[mt]), asbf(bl), sacc[mt][jn], 0, 0, 0);
        }
      }
    }
    // P5a: scale + dist + tanh-clip + exp, in place in sacc
#pragma unroll
    for (int mt = 0; mt < 2; ++mt)
#pragma unroll
      for (int jn = 0; jn < 8; ++jn) {
        int n = w * 128 + jn * 16 + lr;
#pragma unroll
        for (int r = 0; r < 4; ++r) {
          int row = pass * 32 + mt * 16 + lg * 4 + r;
          long off = (bp + row) * (long)Nn + n;
          float sv = fmaf(sacc[mt][jn][r], INV_SQRT_E, -c2 * cdist[off]);
          float logit = 10.0f * fast_tanh(sv) + ninf[off];
          sacc[mt][jn][r] = __expf(logit);
        }
      }
    // P5b: row sums (shfl over 16 lr lanes + cross-wave psum)
#pragma unroll
    for (int mt = 0; mt < 2; ++mt)
#pragma unroll
      for (int r = 0; r < 4; ++r) {
        float v = 0.f;
#pragma unroll
        for (int jn = 0; jn < 8; ++jn) v += sacc[mt][jn][r];
        v += __shfl_xor(v, 1);
        v += __shfl_xor(v, 2);
        v += __shfl_xor(v, 4);
        v += __shfl_xor(v, 8);
        if (lr == 0) psum[(pass * 32 + mt * 16 + lg * 4 + r) * 8 + w] = v;
      }
    __syncthreads();
    if (t < 32) {
      int row = pass * 32 + t;
      float tot = 0.f;
#pragma unroll
      for (int i = 0; i < 8; ++i) tot += psum[row * 8 + i];
      invb[row] = 1.0f / tot;
    }
    __syncthreads();
    // P5c: normalize + store from registers
#pragma unroll
    for (int mt = 0; mt < 2; ++mt)
#pragma unroll
      for (int r = 0; r < 4; ++r) {
        int row = pass * 32 + mt * 16 + lg * 4 + r;
        float inv = invb[row];
        long ro = (bp + row) * (long)Nn + w * 128 + lr;
#pragma unroll
        for (int jn = 0; jn < 8; ++jn) out[ro + jn * 16] = sacc[mt][jn][r] * inv;
      }
  }
}

extern "C" void kernel_launch(void* const* d_in, const int* in_sizes, int n_in,
                              void* d_out, int out_size, void* d_ws, size_t ws_size,
                              hipStream_t stream) {
  const float* nodes = (const float*)d_in[0];
  const float* q1m = (const float*)d_in[1];
  const float* q2m = (const float*)d_in[2];
  const float* lnm = (const float*)d_in[3];
  const float* loadv = (const float*)d_in[4];
  const float* leftv = (const float*)d_in[5];
  const float* cdist = (const float*)d_in[6];
  const float* logs = (const float*)d_in[7];
  const float* ninf = (const float*)d_in[8];
  const float* Wq1 = (const float*)d_in[9];
  const float* Wq2 = (const float*)d_in[10];
  const float* Wql = (const float*)d_in[11];
  const float* Wk = (const float*)d_in[12];
  const float* Wv = (const float*)d_in[13];
  const float* aalpha = (const float*)d_in[14];
  const float* palpha = (const float*)d_in[15];

  char* ws = (char*)d_ws;
  u16* ekkT_hi = (u16*)ws;                            // 16 MB
  u16* ekkT_lo = (u16*)(ws + (16u << 20));            // 16 MB
  u16* nodesP_hi = (u16*)(ws + (32u << 20));          // 8 MB
  u16* nodesP_lo = (u16*)(ws + (40u << 20));          // 8 MB
  u16* wcat_hi = (u16*)(ws + (48u << 20));
  u16* wcat_lo = wcat_hi + 128 * 384;
  u16* wkv_hi = wcat_lo + 128 * 384;
  u16* wkv_lo = wkv_hi + 256 * 128;

  prep_weights<<<2, 256, 0, stream>>>(Wq1, Wq2, Wql, Wk, Wv, wcat_hi, wcat_lo, wkv_hi, wkv_lo);
  kv_prep<<<Bb * Nn / 32, 256, 0, stream>>>(nodes, wkv_hi, wkv_lo, ekkT_hi, ekkT_lo,
                                            nodesP_hi, nodesP_lo);
  main_kernel<<<Bb * Pp / 64, 512, 0, stream>>>(
      q1m, q2m, lnm, loadv, leftv, cdist, ninf, Wql, wcat_hi, wcat_lo, ekkT_hi, ekkT_lo,
      nodesP_hi, nodesP_lo, (float*)d_out, logs, aalpha, palpha);
}